// Round 7
// baseline (306.637 us; speedup 1.0000x reference)
//
#include <hip/hip_runtime.h>
#include <hip/hip_bf16.h>
#include <math.h>

// Problem constants (GPT2Attention: B=2, T=2048, EMBED=768, 12 heads, head=64)
#define NB      2
#define T_SZ    2048
#define EMBEDC  768
#define NHEADS  12
#define HEADD   64
#define QKV_PER (NB * NHEADS * T_SZ * HEADD)   // 3,145,728 elems per q/k/v
// q pre-scale: HEAD^-0.5 * log2(e), so softmax can use exp2 directly
#define QSCALE  0.18033688011112042f

typedef __bf16 bf16x8 __attribute__((ext_vector_type(8)));
typedef float  f32x4  __attribute__((ext_vector_type(4)));

__device__ inline ushort f2bf(float x) {
    union { float f; uint u; } v; v.f = x;
    uint r = v.u + 0x7fffu + ((v.u >> 16) & 1u);   // RNE
    return (ushort)(r >> 16);
}

__device__ inline uint pack2bf(float a, float b) {   // native cvt (RNE), 2x bf16
    union { __bf16 h[2]; uint u; } t;
    t.h[0] = (__bf16)a; t.h[1] = (__bf16)b;
    return t.u;
}

__device__ inline void gload16(const ushort* g, ushort* l) {
    __builtin_amdgcn_global_load_lds(
        (const __attribute__((address_space(1))) unsigned int*)g,
        (__attribute__((address_space(3))) unsigned int*)l, 16, 0, 0);
}

// ---------------------------------------------------------------------------
// f32 -> bf16 elementwise cast (8 elems/thread)
// ---------------------------------------------------------------------------
__global__ __launch_bounds__(256) void cast_k(const float* __restrict__ in,
                                              ushort* __restrict__ out, int n)
{
    int i = (blockIdx.x * 256 + threadIdx.x) * 8;
    if (i >= n) return;
    float4 a = *(const float4*)(in + i);
    float4 b = *(const float4*)(in + i + 4);
    union { ushort u[8]; int4 v; } p;
    p.u[0] = f2bf(a.x); p.u[1] = f2bf(a.y); p.u[2] = f2bf(a.z); p.u[3] = f2bf(a.w);
    p.u[4] = f2bf(b.x); p.u[5] = f2bf(b.y); p.u[6] = f2bf(b.z); p.u[7] = f2bf(b.w);
    *(int4*)(out + i) = p.v;
}

// ---------------------------------------------------------------------------
// Transpose-cast: in[R][C] f32 -> out[C'][R] bf16, 32x32 LDS tile.
// PERM=1 relocates output row n -> mat*768 + (c%12)*64 + c/12 (c = n%768).
// ---------------------------------------------------------------------------
template <int PERM>
__global__ __launch_bounds__(256) void tcast_k(const float* __restrict__ in,
                                               ushort* __restrict__ out,
                                               int R, int C)
{
    __shared__ float t[32][33];
    const int c0 = blockIdx.x * 32, r0 = blockIdx.y * 32;
    const int tx = threadIdx.x & 31, ty = threadIdx.x >> 5;
#pragma unroll
    for (int u = 0; u < 4; ++u)
        t[ty + 8 * u][tx] = in[(size_t)(r0 + ty + 8 * u) * C + c0 + tx];
    __syncthreads();
#pragma unroll
    for (int u = 0; u < 4; ++u) {
        int n = c0 + ty + 8 * u;
        int orow = n;
        if (PERM) {
            int mat = n / EMBEDC, cc = n % EMBEDC;
            orow = mat * EMBEDC + (cc % NHEADS) * HEADD + cc / NHEADS;
        }
        out[(size_t)orow * R + r0 + tx] = f2bf(t[tx][ty + 8 * u]);
    }
}

// ---------------------------------------------------------------------------
// V transpose: in [bh][t][hd] bf16 -> out [bh][hd][t] bf16. 64x64 LDS tile.
// ---------------------------------------------------------------------------
__global__ __launch_bounds__(256) void vt_k(const ushort* __restrict__ in,
                                            ushort* __restrict__ out)
{
    __shared__ ushort tile[64][66];
    const int bh = blockIdx.y;
    const int t0 = blockIdx.x * 64;
    const int tid = threadIdx.x;
#pragma unroll
    for (int u = 0; u < 2; ++u) {
        int s = tid + 256 * u;
        int r = s >> 3, c8 = s & 7;
        *(bf16x8*)&tile[r][c8 * 8] =
            *(const bf16x8*)(in + ((size_t)bh * T_SZ + t0 + r) * HEADD + c8 * 8);
    }
    __syncthreads();
#pragma unroll
    for (int u = 0; u < 2; ++u) {
        int s = tid + 256 * u;
        int hd = s >> 3, tt = s & 7;
        union { ushort v[8]; int4 q; } pk;
#pragma unroll
        for (int j = 0; j < 8; ++j) pk.v[j] = tile[tt * 8 + j][hd];
        *(int4*)(out + ((size_t)bh * HEADD + hd) * T_SZ + t0 + tt * 8) = pk.q;
    }
}

// ---------------------------------------------------------------------------
// bf16 MFMA GEMM, 2-phase double-buffered (unchanged from round 5/6).
// ---------------------------------------------------------------------------
#define STAGE(buf, koff)                                        \
    do {                                                        \
        gload16(gA0 + (koff), &As[buf][lA0o]);                  \
        gload16(gA1 + (koff), &As[buf][lA1o]);                  \
        gload16(gB0 + (koff), &Bs[buf][lB0o]);                  \
        gload16(gB1 + (koff), &Bs[buf][lB1o]);                  \
    } while (0)

template <int MODE>
__global__ __launch_bounds__(256) void gemm_bf16_k(
    const ushort* __restrict__ A, const ushort* __restrict__ Bt,
    const float* __restrict__ bias, void* __restrict__ outp,
    int M, int N, int K)
{
    __shared__ ushort As[2][128 * 32];
    __shared__ ushort Bs[2][128 * 32];

    const int tid = threadIdx.x;
    const int w = tid >> 6, l = tid & 63;
    const int g = l >> 4, r16 = l & 15;
    const int wr = w >> 1, wc = w & 1;
    const int m0 = blockIdx.y * 128, n0 = blockIdx.x * 128;

    const int srow = l >> 2;
    const int scol = ((l & 3) ^ (srow & 3)) * 8;
    const ushort* gA0 = A + (size_t)(m0 + 32 * w + srow) * K + scol;
    const ushort* gA1 = gA0 + (size_t)16 * K;
    const ushort* gB0 = Bt + (size_t)(n0 + 32 * w + srow) * K + scol;
    const ushort* gB1 = gB0 + (size_t)16 * K;
    const int lA0o = (32 * w) * 32,      lA1o = (32 * w + 16) * 32;
    const int lB0o = lA0o,               lB1o = lA1o;

    f32x4 acc[4][4];
#pragma unroll
    for (int i = 0; i < 4; ++i)
#pragma unroll
        for (int j = 0; j < 4; ++j) acc[i][j] = (f32x4){0.f, 0.f, 0.f, 0.f};

    const int rck = (r16 & 3);

    STAGE(0, 0);
    __syncthreads();

    int cur = 0;
    for (int k0 = 0; k0 < K; k0 += 32) {
        if (k0 + 32 < K) STAGE(cur ^ 1, k0 + 32);

        const ushort* sA = As[cur];
        const ushort* sB = Bs[cur];
        bf16x8 af[4], bfr[4];
#pragma unroll
        for (int ms = 0; ms < 4; ++ms) {
            int row = 64 * wr + 16 * ms + r16;
            af[ms] = *(const bf16x8*)&sA[row * 32 + ((g ^ rck) * 8)];
        }
#pragma unroll
        for (int ns = 0; ns < 4; ++ns) {
            int row = 64 * wc + 16 * ns + r16;
            bfr[ns] = *(const bf16x8*)&sB[row * 32 + ((g ^ rck) * 8)];
        }
#pragma unroll
        for (int ms = 0; ms < 4; ++ms)
#pragma unroll
            for (int ns = 0; ns < 4; ++ns)
                acc[ms][ns] = __builtin_amdgcn_mfma_f32_16x16x32_bf16(
                    af[ms], bfr[ns], acc[ms][ns], 0, 0, 0);

        __syncthreads();
        cur ^= 1;
    }

#pragma unroll
    for (int ns = 0; ns < 4; ++ns) {
        const int n = n0 + 64 * wc + 16 * ns + r16;
        if (MODE == 0) {
            float* out = (float*)outp;
            const float bv = bias[n];
#pragma unroll
            for (int ms = 0; ms < 4; ++ms) {
                const int mb = m0 + 64 * wr + 16 * ms + 4 * g;
#pragma unroll
                for (int r = 0; r < 4; ++r)
                    out[(size_t)(mb + r) * N + n] = acc[ms][ns][r] + bv;
            }
        } else {
            ushort* ob = (ushort*)outp;
            const int mat  = n / EMBEDC;   // n is the PERMUTED column n'
            const int c    = n - mat * EMBEDC;
            const int head = c >> 6;
            const int hd   = c & 63;
            const float bv = bias[mat * EMBEDC + hd * NHEADS + head];
            const float qs = (mat == 0) ? QSCALE : 1.f;
#pragma unroll
            for (int ms = 0; ms < 4; ++ms) {
                const int mb = m0 + 64 * wr + 16 * ms + 4 * g;
#pragma unroll
                for (int r = 0; r < 4; ++r) {
                    const int m = mb + r;
                    const int b = m >> 11, t = m & 2047;
                    const size_t bh = (size_t)(b * NHEADS + head);
                    ob[(size_t)mat * QKV_PER + (bh * T_SZ + t) * HEADD + hd] =
                        f2bf((acc[ms][ns][r] + bv) * qs);
                }
            }
        }
    }
}

// ---------------------------------------------------------------------------
// bf16 MFMA flash attention — PAIRED Q-TILES IN ONE 8-WAVE BLOCK.
// q-tiles 2i and 2i+1 both need EXACTLY i+1 kv-tiles of 128, so waves 0-3
// (group A, q-tile 2i) and waves 4-7 (group B, q-tile 2i+1) share the same
// staged K/V tiles in perfect lockstep: staging halved, 8 waves resident.
// Within a group, wave wl owns kv slice [32wl,32wl+32) for all 64 q rows;
// per-wave (m,l,O) partials merged via 3 pairwise LDS rounds per group.
// XCD-affinity mapping: all 16 blocks of one head land on one XCD (its
// 512 KB K/V stays in that XCD's L2); longest blocks dispatch first.
// LDS: Ks[128][64] chunk^=row&7; Vs[64][128] chunk^=row&15 (both-sides XOR).
// ---------------------------------------------------------------------------
__global__ __launch_bounds__(512, 4) void attn_mfma_k(
    const ushort* __restrict__ Qb, const ushort* __restrict__ Kb,
    const ushort* __restrict__ Vtb, ushort* __restrict__ Out)
{
    __shared__ ushort smem[16384];          // 32 KB: K|V tiles, then merge imgs
    __shared__ float Ml[8 * 64], Ll[8 * 64];

    ushort* Ks = smem;                      // [128][64]
    ushort* Vs = smem + 8192;               // [64][128]

    // XCD-affinity: id%8 ~ XCD. Each XCD serves 3 heads; longest block first.
    const int id = blockIdx.x;              // 0..383
    const int xcd = id & 7, slot = id >> 3; // slot 0..47
    const int bh = xcd * 3 + (slot >> 4);
    const int pairIdx = 15 - (slot & 15);
    const int bb = bh / NHEADS, head = bh % NHEADS;
    const int tid = threadIdx.x;
    const int w = tid >> 6, l = tid & 63;
    const int grp = w >> 2, wl = w & 3;     // q-group, kv-slice within group
    const int g = l >> 4, r16 = l & 15;
    const int qb = 2 * pairIdx + grp;
    const int q0 = qb * 64;
    const int nt = pairIdx + 1;             // kv tiles of 128 (both groups!)
    const ushort* Qg = Qb + (size_t)bh * T_SZ * HEADD;
    const ushort* Kg = Kb + (size_t)bh * T_SZ * HEADD;
    const ushort* Vg = Vtb + (size_t)bh * HEADD * T_SZ;

    const int srcLo = ((g & 1) << 5) | r16;
    const int srcHi = srcLo + 16;
    const bool kcSel = (g >> 1) != 0;

    // Q B-frags for the group's 4 q sub-tiles (B[k=d][col=q])
    bf16x8 qf[4][2];
#pragma unroll
    for (int qi = 0; qi < 4; ++qi) {
        const ushort* qp = Qg + (size_t)(q0 + qi * 16 + r16) * HEADD + g * 8;
        qf[qi][0] = *(const bf16x8*)(qp);
        qf[qi][1] = *(const bf16x8*)(qp + 32);
    }

    f32x4 o[4][4];                          // o[dc][qi]
#pragma unroll
    for (int dc = 0; dc < 4; ++dc)
#pragma unroll
        for (int qi = 0; qi < 4; ++qi) o[dc][qi] = (f32x4){0.f, 0.f, 0.f, 0.f};
    float mR[4], lR[4];
#pragma unroll
    for (int qi = 0; qi < 4; ++qi) { mR[qi] = -1e30f; lR[qi] = 0.f; }

    // stage tile 0 (512 threads, 2 chunks each)
    bf16x8 kr[2], vr[2];
#pragma unroll
    for (int u = 0; u < 2; ++u) {
        int s = tid + 512 * u;
        kr[u] = *(const bf16x8*)(Kg + (size_t)(s >> 3) * HEADD + (s & 7) * 8);
        vr[u] = *(const bf16x8*)(Vg + (size_t)(s >> 4) * T_SZ + (s & 15) * 8);
    }
#pragma unroll
    for (int u = 0; u < 2; ++u) {
        int s = tid + 512 * u;
        int krow = s >> 3, kc8 = s & 7;
        int vrow = s >> 4, vc16 = s & 15;
        *(bf16x8*)&Ks[krow * 64 + ((kc8 ^ (krow & 7)) * 8)] = kr[u];
        *(bf16x8*)&Vs[vrow * 128 + ((vc16 ^ (vrow & 15)) * 8)] = vr[u];
    }
    __syncthreads();

    for (int kt = 0; kt < nt; ++kt) {
        if (kt + 1 < nt) {                  // T14 reg-prefetch next tile
            const int k1 = (kt + 1) * 128;
#pragma unroll
            for (int u = 0; u < 2; ++u) {
                int s = tid + 512 * u;
                kr[u] = *(const bf16x8*)(Kg + (size_t)(k1 + (s >> 3)) * HEADD +
                                         (s & 7) * 8);
                vr[u] = *(const bf16x8*)(Vg + (size_t)(s >> 4) * T_SZ + k1 +
                                         (s & 15) * 8);
            }
        }

        // group A's last tile only needs kv slices 0,1 (upper 64 kv all masked)
        const bool act = !(kt == nt - 1 && grp == 0 && wl >= 2);
        if (act) {
            // S^T[kv-slice][q]: 2 kc x 4 qi, K frags reused across qi
            f32x4 st[2][4];
#pragma unroll
            for (int kc = 0; kc < 2; ++kc) {
                int row = 32 * wl + kc * 16 + r16;
                const ushort* kp = &Ks[row * 64];
                bf16x8 a0 = *(const bf16x8*)(kp + ((g    ) ^ (r16 & 7)) * 8);
                bf16x8 a1 = *(const bf16x8*)(kp + ((g + 4) ^ (r16 & 7)) * 8);
#pragma unroll
                for (int qi = 0; qi < 4; ++qi) {
                    f32x4 c = (f32x4){0.f, 0.f, 0.f, 0.f};
                    c = __builtin_amdgcn_mfma_f32_16x16x32_bf16(a0, qf[qi][0], c, 0, 0, 0);
                    c = __builtin_amdgcn_mfma_f32_16x16x32_bf16(a1, qf[qi][1], c, 0, 0, 0);
                    st[kc][qi] = c;
                }
            }

            if (kt == nt - 1) {             // causal mask, last tile only
                const int kvb = kt * 128 + 32 * wl;
#pragma unroll
                for (int kc = 0; kc < 2; ++kc)
#pragma unroll
                    for (int qi = 0; qi < 4; ++qi)
#pragma unroll
                        for (int r = 0; r < 4; ++r)
                            if (kvb + kc * 16 + 4 * g + r > q0 + qi * 16 + r16)
                                st[kc][qi][r] = -1e30f;
            }

            // online softmax per qi (lane owns q-col r16; reduce across g)
            float pm[4];
#pragma unroll
            for (int qi = 0; qi < 4; ++qi) {
                float m = fmaxf(fmaxf(st[0][qi][0], st[0][qi][1]),
                                fmaxf(st[0][qi][2], st[0][qi][3]));
                m = fmaxf(m, fmaxf(fmaxf(st[1][qi][0], st[1][qi][1]),
                                   fmaxf(st[1][qi][2], st[1][qi][3])));
                m = fmaxf(m, __shfl_xor(m, 16));
                m = fmaxf(m, __shfl_xor(m, 32));
                pm[qi] = m;
            }
            float dm = fmaxf(fmaxf(pm[0] - mR[0], pm[1] - mR[1]),
                             fmaxf(pm[2] - mR[2], pm[3] - mR[3]));
            if (!__all(dm <= 8.f)) {        // T13 defer-max
#pragma unroll
                for (int qi = 0; qi < 4; ++qi) {
                    float mNew = fmaxf(mR[qi], pm[qi]);
                    float sc = exp2f(mR[qi] - mNew);
                    lR[qi] *= sc;
                    mR[qi] = mNew;
#pragma unroll
                    for (int dc = 0; dc < 4; ++dc) o[dc][qi] *= sc;
                }
            }
#pragma unroll
            for (int qi = 0; qi < 4; ++qi) {
                float rs = 0.f;
#pragma unroll
                for (int kc = 0; kc < 2; ++kc)
#pragma unroll
                    for (int r = 0; r < 4; ++r) {
                        float e = exp2f(st[kc][qi][r] - mR[qi]);
                        st[kc][qi][r] = e;
                        rs += e;
                    }
                rs += __shfl_xor(rs, 16);
                rs += __shfl_xor(rs, 32);
                lR[qi] += rs;
            }

            // pack P^T
            uint pk[4][2][2];
#pragma unroll
            for (int qi = 0; qi < 4; ++qi)
#pragma unroll
                for (int kc = 0; kc < 2; ++kc) {
                    pk[qi][kc][0] = pack2bf(st[kc][qi][0], st[kc][qi][1]);
                    pk[qi][kc][1] = pack2bf(st[kc][qi][2], st[kc][qi][3]);
                }

            // V^T A-frags (shared across qi): slice cols 32wl..+32
            bf16x8 vf[4];
#pragma unroll
            for (int dc = 0; dc < 4; ++dc) {
                int row = dc * 16 + r16;
                vf[dc] = *(const bf16x8*)
                    &Vs[row * 128 + (((4 * wl + g) ^ (row & 15)) * 8)];
            }

            // redistribute P^T to B-frags + PV MFMAs
#pragma unroll
            for (int qi = 0; qi < 4; ++qi) {
                uint A0 = (uint)__shfl((int)pk[qi][0][0], srcLo);
                uint A1 = (uint)__shfl((int)pk[qi][0][1], srcLo);
                uint B0 = (uint)__shfl((int)pk[qi][1][0], srcLo);
                uint B1 = (uint)__shfl((int)pk[qi][1][1], srcLo);
                uint A2 = (uint)__shfl((int)pk[qi][0][0], srcHi);
                uint A3 = (uint)__shfl((int)pk[qi][0][1], srcHi);
                uint B2 = (uint)__shfl((int)pk[qi][1][0], srcHi);
                uint B3 = (uint)__shfl((int)pk[qi][1][1], srcHi);
                union { uint u[4]; bf16x8 v; } t;
                t.u[0] = kcSel ? B0 : A0;
                t.u[1] = kcSel ? B1 : A1;
                t.u[2] = kcSel ? B2 : A2;
                t.u[3] = kcSel ? B3 : A3;
#pragma unroll
                for (int dc = 0; dc < 4; ++dc)
                    o[dc][qi] = __builtin_amdgcn_mfma_f32_16x16x32_bf16(
                        vf[dc], t.v, o[dc][qi], 0, 0, 0);
            }
        }

        __syncthreads();                    // all waves done reading tile kt
        if (kt + 1 < nt) {
#pragma unroll
            for (int u = 0; u < 2; ++u) {
                int s = tid + 512 * u;
                int krow = s >> 3, kc8 = s & 7;
                int vrow = s >> 4, vc16 = s & 15;
                *(bf16x8*)&Ks[krow * 64 + ((kc8 ^ (krow & 7)) * 8)] = kr[u];
                *(bf16x8*)&Vs[vrow * 128 + ((vc16 ^ (vrow & 15)) * 8)] = vr[u];
            }
            __syncthreads();                // tile kt+1 ready
        }
    }

    // ---- cross-wave merge of (m, l, O) within each q-group ----
    if (g == 0) {
#pragma unroll
        for (int qi = 0; qi < 4; ++qi) {
            Ml[w * 64 + qi * 16 + r16] = mR[qi];
            Ll[w * 64 + qi * 16 + r16] = lR[qi];
        }
    }
    __syncthreads();

    float lt[4];
    {
        const int base = grp * 256;
#pragma unroll
        for (int qi = 0; qi < 4; ++qi) {
            const int ix = base + qi * 16 + r16;
            float m0 = Ml[ix], m1 = Ml[ix + 64], m2 = Ml[ix + 128], m3 = Ml[ix + 192];
            float mt = fmaxf(fmaxf(m0, m1), fmaxf(m2, m3));
            float f = exp2f(mR[qi] - mt);
#pragma unroll
            for (int dc = 0; dc < 4; ++dc) o[dc][qi] *= f;
            lt[qi] = Ll[ix]       * exp2f(m0 - mt) + Ll[ix + 64]  * exp2f(m1 - mt)
                   + Ll[ix + 128] * exp2f(m2 - mt) + Ll[ix + 192] * exp2f(m3 - mt);
        }
    }

    // 3 pairwise rounds into one 16 KB f32 image per group (chunk-XOR swz).
    float* img = (float*)smem + grp * 4096;
#pragma unroll
    for (int rnd = 1; rnd <= 3; ++rnd) {
        if (wl == rnd) {
#pragma unroll
            for (int dc = 0; dc < 4; ++dc)
#pragma unroll
                for (int qi = 0; qi < 4; ++qi)
                    *(f32x4*)&img[(qi * 16 + r16) * 64 + (((dc * 4 + g) ^ r16) & 15) * 4]
                        = o[dc][qi];
        }
        __syncthreads();
        if (wl == 0) {
#pragma unroll
            for (int dc = 0; dc < 4; ++dc)
#pragma unroll
                for (int qi = 0; qi < 4; ++qi)
                    o[dc][qi] += *(const f32x4*)
                        &img[(qi * 16 + r16) * 64 + (((dc * 4 + g) ^ r16) & 15) * 4];
        }
        __syncthreads();
    }

    // epilogue: wl==0 wave of each group writes att bf16 [b][t=q][head*64+d]
    if (wl == 0) {
#pragma unroll
        for (int qi = 0; qi < 4; ++qi) {
            const float inv = 1.f / lt[qi];
            ushort* orow = Out + ((size_t)(bb * T_SZ + q0 + qi * 16 + r16)) * EMBEDC
                         + head * HEADD;
#pragma unroll
            for (int dc = 0; dc < 4; ++dc) {
                ushort4 pv;
                pv.x = f2bf(o[dc][qi][0] * inv);
                pv.y = f2bf(o[dc][qi][1] * inv);
                pv.z = f2bf(o[dc][qi][2] * inv);
                pv.w = f2bf(o[dc][qi][3] * inv);
                *(ushort4*)(orow + dc * 16 + 4 * g) = pv;
            }
        }
    }
}

// ---------------------------------------------------------------------------
extern "C" void kernel_launch(void* const* d_in, const int* in_sizes, int n_in,
                              void* d_out, int out_size, void* d_ws, size_t ws_size,
                              hipStream_t stream)
{
    const float* x      = (const float*)d_in[0];   // [2,2048,768]
    const float* w_attn = (const float*)d_in[1];   // [768,2304]
    const float* b_attn = (const float*)d_in[2];   // [2304]
    const float* w_proj = (const float*)d_in[3];   // [768,768]
    const float* b_proj = (const float*)d_in[4];   // [768]
    float* out = (float*)d_out;                    // [2,2048,768] f32

    // Workspace (ushort units): q,k,v | vT | att | x_bf | w_attnT' | w_projT
    ushort* qw   = (ushort*)d_ws;                  // 3*QKV_PER  [mat][bh][t][hd]
    ushort* vT   = qw + (size_t)3 * QKV_PER;       // QKV_PER    [bh][hd][t]
    ushort* attb = vT + QKV_PER;                   // QKV_PER
    ushort* xb   = attb + QKV_PER;                 // QKV_PER
    ushort* waT  = xb + QKV_PER;                   // 768*2304 (col-permuted)
    ushort* wpT  = waT + (size_t)EMBEDC * 3 * EMBEDC;

    cast_k<<<QKV_PER / (256 * 8), 256, 0, stream>>>(x, xb, QKV_PER);
    tcast_k<1><<<dim3(3 * EMBEDC / 32, EMBEDC / 32), 256, 0, stream>>>(
        w_attn, waT, EMBEDC, 3 * EMBEDC);
    tcast_k<0><<<dim3(EMBEDC / 32, EMBEDC / 32), 256, 0, stream>>>(
        w_proj, wpT, EMBEDC, EMBEDC);

    // K1: qkv = x @ w_attn + b_attn -> bf16 q/k/v [bh][t][hd]
    gemm_bf16_k<1><<<dim3(2304 / 128, 4096 / 128), 256, 0, stream>>>(
        xb, waT, b_attn, qw, NB * T_SZ, 3 * EMBEDC, EMBEDC);

    // V transpose -> [bh][hd][t]
    vt_k<<<dim3(T_SZ / 64, NB * NHEADS), 256, 0, stream>>>(
        qw + 2 * (size_t)QKV_PER, vT);

    // K2: bf16 MFMA causal flash attention (8-wave paired q-tiles)
    attn_mfma_k<<<384, 512, 0, stream>>>(
        qw, qw + QKV_PER, vT, attb);

    // K3: out = att @ w_proj + b_proj (f32 out)
    gemm_bf16_k<0><<<dim3(768 / 128, 4096 / 128), 256, 0, stream>>>(
        attb, wpT, b_proj, out, NB * T_SZ, EMBEDC, EMBEDC);
}

// Round 8
// 127.107 us; speedup vs baseline: 2.4124x; 2.4124x over previous
//
#include <hip/hip_runtime.h>
#include <hip/hip_bf16.h>
#include <math.h>

// Problem constants (GPT2Attention: B=2, T=2048, EMBED=768, 12 heads, head=64)
#define NB      2
#define T_SZ    2048
#define EMBEDC  768
#define NHEADS  12
#define HEADD   64
#define QKV_PER (NB * NHEADS * T_SZ * HEADD)   // 3,145,728 elems per q/k/v
// q pre-scale: HEAD^-0.5 * log2(e), so softmax can use exp2 directly
#define QSCALE  0.18033688011112042f

typedef __bf16 bf16x8 __attribute__((ext_vector_type(8)));
typedef float  f32x4  __attribute__((ext_vector_type(4)));

__device__ inline ushort f2bf(float x) {
    union { float f; uint u; } v; v.f = x;
    uint r = v.u + 0x7fffu + ((v.u >> 16) & 1u);   // RNE
    return (ushort)(r >> 16);
}

__device__ inline uint pack2bf(float a, float b) {   // native cvt (RNE), 2x bf16
    union { __bf16 h[2]; uint u; } t;
    t.h[0] = (__bf16)a; t.h[1] = (__bf16)b;
    return t.u;
}

__device__ inline void gload16(const ushort* g, ushort* l) {
    __builtin_amdgcn_global_load_lds(
        (const __attribute__((address_space(1))) unsigned int*)g,
        (__attribute__((address_space(3))) unsigned int*)l, 16, 0, 0);
}

// ---------------------------------------------------------------------------
// f32 -> bf16 elementwise cast (8 elems/thread)
// ---------------------------------------------------------------------------
__global__ __launch_bounds__(256) void cast_k(const float* __restrict__ in,
                                              ushort* __restrict__ out, int n)
{
    int i = (blockIdx.x * 256 + threadIdx.x) * 8;
    if (i >= n) return;
    float4 a = *(const float4*)(in + i);
    float4 b = *(const float4*)(in + i + 4);
    union { ushort u[8]; int4 v; } p;
    p.u[0] = f2bf(a.x); p.u[1] = f2bf(a.y); p.u[2] = f2bf(a.z); p.u[3] = f2bf(a.w);
    p.u[4] = f2bf(b.x); p.u[5] = f2bf(b.y); p.u[6] = f2bf(b.z); p.u[7] = f2bf(b.w);
    *(int4*)(out + i) = p.v;
}

// ---------------------------------------------------------------------------
// Transpose-cast: in[R][C] f32 -> out[C'][R] bf16, 32x32 LDS tile.
// PERM=1 relocates output row n -> mat*768 + (c%12)*64 + c/12 (c = n%768).
// ---------------------------------------------------------------------------
template <int PERM>
__global__ __launch_bounds__(256) void tcast_k(const float* __restrict__ in,
                                               ushort* __restrict__ out,
                                               int R, int C)
{
    __shared__ float t[32][33];
    const int c0 = blockIdx.x * 32, r0 = blockIdx.y * 32;
    const int tx = threadIdx.x & 31, ty = threadIdx.x >> 5;
#pragma unroll
    for (int u = 0; u < 4; ++u)
        t[ty + 8 * u][tx] = in[(size_t)(r0 + ty + 8 * u) * C + c0 + tx];
    __syncthreads();
#pragma unroll
    for (int u = 0; u < 4; ++u) {
        int n = c0 + ty + 8 * u;
        int orow = n;
        if (PERM) {
            int mat = n / EMBEDC, cc = n % EMBEDC;
            orow = mat * EMBEDC + (cc % NHEADS) * HEADD + cc / NHEADS;
        }
        out[(size_t)orow * R + r0 + tx] = f2bf(t[tx][ty + 8 * u]);
    }
}

// ---------------------------------------------------------------------------
// V transpose: in [bh][t][hd] bf16 -> out [bh][hd][t] bf16. 64x64 LDS tile.
// ---------------------------------------------------------------------------
__global__ __launch_bounds__(256) void vt_k(const ushort* __restrict__ in,
                                            ushort* __restrict__ out)
{
    __shared__ ushort tile[64][66];
    const int bh = blockIdx.y;
    const int t0 = blockIdx.x * 64;
    const int tid = threadIdx.x;
#pragma unroll
    for (int u = 0; u < 2; ++u) {
        int s = tid + 256 * u;
        int r = s >> 3, c8 = s & 7;
        *(bf16x8*)&tile[r][c8 * 8] =
            *(const bf16x8*)(in + ((size_t)bh * T_SZ + t0 + r) * HEADD + c8 * 8);
    }
    __syncthreads();
#pragma unroll
    for (int u = 0; u < 2; ++u) {
        int s = tid + 256 * u;
        int hd = s >> 3, tt = s & 7;
        union { ushort v[8]; int4 q; } pk;
#pragma unroll
        for (int j = 0; j < 8; ++j) pk.v[j] = tile[tt * 8 + j][hd];
        *(int4*)(out + ((size_t)bh * HEADD + hd) * T_SZ + t0 + tt * 8) = pk.q;
    }
}

// ---------------------------------------------------------------------------
// bf16 MFMA GEMM, 2-phase double-buffered (unchanged from round 5/6).
// ---------------------------------------------------------------------------
#define STAGE(buf, koff)                                        \
    do {                                                        \
        gload16(gA0 + (koff), &As[buf][lA0o]);                  \
        gload16(gA1 + (koff), &As[buf][lA1o]);                  \
        gload16(gB0 + (koff), &Bs[buf][lB0o]);                  \
        gload16(gB1 + (koff), &Bs[buf][lB1o]);                  \
    } while (0)

template <int MODE>
__global__ __launch_bounds__(256) void gemm_bf16_k(
    const ushort* __restrict__ A, const ushort* __restrict__ Bt,
    const float* __restrict__ bias, void* __restrict__ outp,
    int M, int N, int K)
{
    __shared__ ushort As[2][128 * 32];
    __shared__ ushort Bs[2][128 * 32];

    const int tid = threadIdx.x;
    const int w = tid >> 6, l = tid & 63;
    const int g = l >> 4, r16 = l & 15;
    const int wr = w >> 1, wc = w & 1;
    const int m0 = blockIdx.y * 128, n0 = blockIdx.x * 128;

    const int srow = l >> 2;
    const int scol = ((l & 3) ^ (srow & 3)) * 8;
    const ushort* gA0 = A + (size_t)(m0 + 32 * w + srow) * K + scol;
    const ushort* gA1 = gA0 + (size_t)16 * K;
    const ushort* gB0 = Bt + (size_t)(n0 + 32 * w + srow) * K + scol;
    const ushort* gB1 = gB0 + (size_t)16 * K;
    const int lA0o = (32 * w) * 32,      lA1o = (32 * w + 16) * 32;
    const int lB0o = lA0o,               lB1o = lA1o;

    f32x4 acc[4][4];
#pragma unroll
    for (int i = 0; i < 4; ++i)
#pragma unroll
        for (int j = 0; j < 4; ++j) acc[i][j] = (f32x4){0.f, 0.f, 0.f, 0.f};

    const int rck = (r16 & 3);

    STAGE(0, 0);
    __syncthreads();

    int cur = 0;
    for (int k0 = 0; k0 < K; k0 += 32) {
        if (k0 + 32 < K) STAGE(cur ^ 1, k0 + 32);

        const ushort* sA = As[cur];
        const ushort* sB = Bs[cur];
        bf16x8 af[4], bfr[4];
#pragma unroll
        for (int ms = 0; ms < 4; ++ms) {
            int row = 64 * wr + 16 * ms + r16;
            af[ms] = *(const bf16x8*)&sA[row * 32 + ((g ^ rck) * 8)];
        }
#pragma unroll
        for (int ns = 0; ns < 4; ++ns) {
            int row = 64 * wc + 16 * ns + r16;
            bfr[ns] = *(const bf16x8*)&sB[row * 32 + ((g ^ rck) * 8)];
        }
#pragma unroll
        for (int ms = 0; ms < 4; ++ms)
#pragma unroll
            for (int ns = 0; ns < 4; ++ns)
                acc[ms][ns] = __builtin_amdgcn_mfma_f32_16x16x32_bf16(
                    af[ms], bfr[ns], acc[ms][ns], 0, 0, 0);

        __syncthreads();
        cur ^= 1;
    }

#pragma unroll
    for (int ns = 0; ns < 4; ++ns) {
        const int n = n0 + 64 * wc + 16 * ns + r16;
        if (MODE == 0) {
            float* out = (float*)outp;
            const float bv = bias[n];
#pragma unroll
            for (int ms = 0; ms < 4; ++ms) {
                const int mb = m0 + 64 * wr + 16 * ms + 4 * g;
#pragma unroll
                for (int r = 0; r < 4; ++r)
                    out[(size_t)(mb + r) * N + n] = acc[ms][ns][r] + bv;
            }
        } else {
            ushort* ob = (ushort*)outp;
            const int mat  = n / EMBEDC;   // n is the PERMUTED column n'
            const int c    = n - mat * EMBEDC;
            const int head = c >> 6;
            const int hd   = c & 63;
            const float bv = bias[mat * EMBEDC + hd * NHEADS + head];
            const float qs = (mat == 0) ? QSCALE : 1.f;
#pragma unroll
            for (int ms = 0; ms < 4; ++ms) {
                const int mb = m0 + 64 * wr + 16 * ms + 4 * g;
#pragma unroll
                for (int r = 0; r < 4; ++r) {
                    const int m = mb + r;
                    const int b = m >> 11, t = m & 2047;
                    const size_t bh = (size_t)(b * NHEADS + head);
                    ob[(size_t)mat * QKV_PER + (bh * T_SZ + t) * HEADD + hd] =
                        f2bf((acc[ms][ns][r] + bv) * qs);
                }
            }
        }
    }
}

// ---------------------------------------------------------------------------
// bf16 MFMA flash attention — 32-ROW Q-TILES, PAIRED (i, 63-i), 4 WAVES.
// Grid (768): block b -> (bh = b>>5, p = b&31); reps i = p then 63-p.
// Every block does EXACTLY 17 kv-tiles total -> uniform; 768 = 3 blocks/CU.
// Per 128-kv tile, wave w owns kv-slice [32w,32w+32) for all 32 q rows
// (2 q-frags). Staging via global_load_lds (linear LDS dest in lane order,
// pre-swizzled GLOBAL source chunk; rule 21). Per-wave (m,l,O) merged via
// parallel image reduction: all 4 waves publish swizzled f32 images, wave w
// gathers d-range [16w,16w+16) across images and writes bf16 out.
// LDS: Ks[128][64] chunk^=row&7; Vs[64][128] chunk^=row&15; reused as images.
// ---------------------------------------------------------------------------
#define ASTAGE(k0)                                                            \
    do {                                                                      \
        _Pragma("unroll")                                                     \
        for (int u = 0; u < 4; ++u) {                                         \
            int s = tid + 256 * u;                                            \
            int krow = s >> 3, kc8 = s & 7;                                   \
            gload16(Kg + (size_t)((k0) + krow) * HEADD +                      \
                        ((kc8 ^ (krow & 7)) * 8),                             \
                    Ks + (64 * w + 256 * u) * 8);                             \
            int vrow = s >> 4, vc16 = s & 15;                                 \
            gload16(Vg + (size_t)vrow * T_SZ + (k0) +                         \
                        ((vc16 ^ (vrow & 15)) * 8),                           \
                    Vs + (64 * w + 256 * u) * 8);                             \
        }                                                                     \
    } while (0)

__global__ __launch_bounds__(256) void attn_mfma_k(
    const ushort* __restrict__ Qb, const ushort* __restrict__ Kb,
    const ushort* __restrict__ Vtb, ushort* __restrict__ Out)
{
    __shared__ ushort smem[16384];          // 32 KB: K|V tiles, then 4 f32 imgs
    __shared__ float Ml[128], Ll[128];      // [wave][32 q-rows]

    ushort* Ks = smem;                      // [128][64]
    ushort* Vs = smem + 8192;               // [64][128]
    float*  fsm = (float*)smem;             // merge images, 4 x 2048 f32

    const int bh = blockIdx.x >> 5;
    const int p  = blockIdx.x & 31;
    const int bb = bh / NHEADS, head = bh % NHEADS;
    const int tid = threadIdx.x;
    const int w = tid >> 6, l = tid & 63;
    const int g = l >> 4, r16 = l & 15;
    const ushort* Qg = Qb + (size_t)bh * T_SZ * HEADD;
    const ushort* Kg = Kb + (size_t)bh * T_SZ * HEADD;
    const ushort* Vg = Vtb + (size_t)bh * HEADD * T_SZ;

    const int srcLo = ((g & 1) << 5) | r16;
    const int srcHi = srcLo + 16;
    const bool kcSel = (g >> 1) != 0;

    for (int rep = 0; rep < 2; ++rep) {
        const int iq = rep ? (63 - p) : p;
        const int q0 = iq * 32;
        const int qmax = q0 + 31;
        const int nt = iq / 4 + 1;          // kv tiles of 128

        // Q B-frags (2 q sub-tiles of 16)
        bf16x8 qf[2][2];
#pragma unroll
        for (int qi = 0; qi < 2; ++qi) {
            const ushort* qp = Qg + (size_t)(q0 + qi * 16 + r16) * HEADD + g * 8;
            qf[qi][0] = *(const bf16x8*)(qp);
            qf[qi][1] = *(const bf16x8*)(qp + 32);
        }

        f32x4 o[4][2];                      // o[dc][qi]
#pragma unroll
        for (int dc = 0; dc < 4; ++dc)
#pragma unroll
            for (int qi = 0; qi < 2; ++qi) o[dc][qi] = (f32x4){0.f, 0.f, 0.f, 0.f};
        float mR[2] = {-1e30f, -1e30f}, lR[2] = {0.f, 0.f};

        __syncthreads();                    // smem free (prev rep images read)
        ASTAGE(0);
        __syncthreads();                    // tile 0 landed (vmcnt drained)

        for (int kt = 0; kt < nt; ++kt) {
            const int kvb = kt * 128 + 32 * w;
            const bool act = (kt + 1 < nt) || (kvb <= qmax);
            if (act) {
                // S^T[kv-slice][q]: 2 kc x 2 qi
                f32x4 st[2][2];
#pragma unroll
                for (int kc = 0; kc < 2; ++kc) {
                    int row = 32 * w + kc * 16 + r16;
                    const ushort* kp = &Ks[row * 64];
                    bf16x8 a0 = *(const bf16x8*)(kp + ((g    ) ^ (r16 & 7)) * 8);
                    bf16x8 a1 = *(const bf16x8*)(kp + ((g + 4) ^ (r16 & 7)) * 8);
#pragma unroll
                    for (int qi = 0; qi < 2; ++qi) {
                        f32x4 c = (f32x4){0.f, 0.f, 0.f, 0.f};
                        c = __builtin_amdgcn_mfma_f32_16x16x32_bf16(a0, qf[qi][0], c, 0, 0, 0);
                        c = __builtin_amdgcn_mfma_f32_16x16x32_bf16(a1, qf[qi][1], c, 0, 0, 0);
                        st[kc][qi] = c;
                    }
                }

                if (kt == nt - 1) {         // causal mask (diagonal tile)
#pragma unroll
                    for (int kc = 0; kc < 2; ++kc)
#pragma unroll
                        for (int qi = 0; qi < 2; ++qi)
#pragma unroll
                            for (int r = 0; r < 4; ++r)
                                if (kvb + kc * 16 + 4 * g + r > q0 + qi * 16 + r16)
                                    st[kc][qi][r] = -1e30f;
                }

                // online softmax per qi (lane owns q-col r16; reduce across g)
                float pm[2];
#pragma unroll
                for (int qi = 0; qi < 2; ++qi) {
                    float m = fmaxf(fmaxf(st[0][qi][0], st[0][qi][1]),
                                    fmaxf(st[0][qi][2], st[0][qi][3]));
                    m = fmaxf(m, fmaxf(fmaxf(st[1][qi][0], st[1][qi][1]),
                                       fmaxf(st[1][qi][2], st[1][qi][3])));
                    m = fmaxf(m, __shfl_xor(m, 16));
                    m = fmaxf(m, __shfl_xor(m, 32));
                    pm[qi] = m;
                }
                float dm = fmaxf(pm[0] - mR[0], pm[1] - mR[1]);
                if (!__all(dm <= 8.f)) {    // T13 defer-max
#pragma unroll
                    for (int qi = 0; qi < 2; ++qi) {
                        float mNew = fmaxf(mR[qi], pm[qi]);
                        float sc = exp2f(mR[qi] - mNew);
                        lR[qi] *= sc;
                        mR[qi] = mNew;
#pragma unroll
                        for (int dc = 0; dc < 4; ++dc) o[dc][qi] *= sc;
                    }
                }
#pragma unroll
                for (int qi = 0; qi < 2; ++qi) {
                    float rs = 0.f;
#pragma unroll
                    for (int kc = 0; kc < 2; ++kc)
#pragma unroll
                        for (int r = 0; r < 4; ++r) {
                            float e = exp2f(st[kc][qi][r] - mR[qi]);
                            st[kc][qi][r] = e;
                            rs += e;
                        }
                    rs += __shfl_xor(rs, 16);
                    rs += __shfl_xor(rs, 32);
                    lR[qi] += rs;
                }

                // pack P^T
                uint pk[2][2][2];
#pragma unroll
                for (int qi = 0; qi < 2; ++qi)
#pragma unroll
                    for (int kc = 0; kc < 2; ++kc) {
                        pk[qi][kc][0] = pack2bf(st[kc][qi][0], st[kc][qi][1]);
                        pk[qi][kc][1] = pack2bf(st[kc][qi][2], st[kc][qi][3]);
                    }

                // V^T A-frags: slice cols 32w..+32
                bf16x8 vf[4];
#pragma unroll
                for (int dc = 0; dc < 4; ++dc) {
                    int row = dc * 16 + r16;
                    vf[dc] = *(const bf16x8*)
                        &Vs[row * 128 + (((4 * w + g) ^ r16) * 8)];
                }

                // redistribute P^T to B-frags + PV MFMAs
#pragma unroll
                for (int qi = 0; qi < 2; ++qi) {
                    uint A0 = (uint)__shfl((int)pk[qi][0][0], srcLo);
                    uint A1 = (uint)__shfl((int)pk[qi][0][1], srcLo);
                    uint B0 = (uint)__shfl((int)pk[qi][1][0], srcLo);
                    uint B1 = (uint)__shfl((int)pk[qi][1][1], srcLo);
                    uint A2 = (uint)__shfl((int)pk[qi][0][0], srcHi);
                    uint A3 = (uint)__shfl((int)pk[qi][0][1], srcHi);
                    uint B2 = (uint)__shfl((int)pk[qi][1][0], srcHi);
                    uint B3 = (uint)__shfl((int)pk[qi][1][1], srcHi);
                    union { uint u[4]; bf16x8 v; } t;
                    t.u[0] = kcSel ? B0 : A0;
                    t.u[1] = kcSel ? B1 : A1;
                    t.u[2] = kcSel ? B2 : A2;
                    t.u[3] = kcSel ? B3 : A3;
#pragma unroll
                    for (int dc = 0; dc < 4; ++dc)
                        o[dc][qi] = __builtin_amdgcn_mfma_f32_16x16x32_bf16(
                            vf[dc], t.v, o[dc][qi], 0, 0, 0);
                }
            }

            __syncthreads();                // all waves done reading tile kt
            if (kt + 1 < nt) {
                ASTAGE((kt + 1) * 128);
                __syncthreads();            // tile kt+1 landed
            }
        }

        // ---- parallel cross-wave merge ----
        if (g == 0) {
#pragma unroll
            for (int qi = 0; qi < 2; ++qi) {
                Ml[w * 32 + qi * 16 + r16] = mR[qi];
                Ll[w * 32 + qi * 16 + r16] = lR[qi];
            }
        }
        __syncthreads();

        float lt[2];
#pragma unroll
        for (int qi = 0; qi < 2; ++qi) {
            const int ix = qi * 16 + r16;
            float m0 = Ml[ix], m1 = Ml[32 + ix], m2 = Ml[64 + ix], m3 = Ml[96 + ix];
            float mt = fmaxf(fmaxf(m0, m1), fmaxf(m2, m3));
            float f = exp2f(mR[qi] - mt);
#pragma unroll
            for (int dc = 0; dc < 4; ++dc) o[dc][qi] *= f;
            lt[qi] = Ll[ix]      * exp2f(m0 - mt) + Ll[32 + ix] * exp2f(m1 - mt)
                   + Ll[64 + ix] * exp2f(m2 - mt) + Ll[96 + ix] * exp2f(m3 - mt);
        }

        // publish scaled O images (swizzled chunk: (dc*4+g)^r16)
#pragma unroll
        for (int dc = 0; dc < 4; ++dc)
#pragma unroll
            for (int qi = 0; qi < 2; ++qi)
                *(f32x4*)&fsm[w * 2048 + (qi * 16 + r16) * 64 +
                              (((dc * 4 + g) ^ r16) * 4)] = o[dc][qi];
        __syncthreads();

        // gather: wave w sums d-range [16w,16w+16) across the 4 images
#pragma unroll
        for (int qi = 0; qi < 2; ++qi) {
            const int off = (qi * 16 + r16) * 64 + (((w * 4 + g) ^ r16) * 4);
            f32x4 a = *(const f32x4*)&fsm[off];
            a += *(const f32x4*)&fsm[2048 + off];
            a += *(const f32x4*)&fsm[4096 + off];
            a += *(const f32x4*)&fsm[6144 + off];
            const float inv = 1.f / lt[qi];
            ushort4 pv;
            pv.x = f2bf(a[0] * inv);
            pv.y = f2bf(a[1] * inv);
            pv.z = f2bf(a[2] * inv);
            pv.w = f2bf(a[3] * inv);
            *(ushort4*)(Out + ((size_t)(bb * T_SZ + q0 + qi * 16 + r16)) * EMBEDC
                        + head * HEADD + w * 16 + 4 * g) = pv;
        }
        // next rep's first __syncthreads guards image reuse
    }
}

// ---------------------------------------------------------------------------
extern "C" void kernel_launch(void* const* d_in, const int* in_sizes, int n_in,
                              void* d_out, int out_size, void* d_ws, size_t ws_size,
                              hipStream_t stream)
{
    const float* x      = (const float*)d_in[0];   // [2,2048,768]
    const float* w_attn = (const float*)d_in[1];   // [768,2304]
    const float* b_attn = (const float*)d_in[2];   // [2304]
    const float* w_proj = (const float*)d_in[3];   // [768,768]
    const float* b_proj = (const float*)d_in[4];   // [768]
    float* out = (float*)d_out;                    // [2,2048,768] f32

    // Workspace (ushort units): q,k,v | vT | att | x_bf | w_attnT' | w_projT
    ushort* qw   = (ushort*)d_ws;                  // 3*QKV_PER  [mat][bh][t][hd]
    ushort* vT   = qw + (size_t)3 * QKV_PER;       // QKV_PER    [bh][hd][t]
    ushort* attb = vT + QKV_PER;                   // QKV_PER
    ushort* xb   = attb + QKV_PER;                 // QKV_PER
    ushort* waT  = xb + QKV_PER;                   // 768*2304 (col-permuted)
    ushort* wpT  = waT + (size_t)EMBEDC * 3 * EMBEDC;

    cast_k<<<QKV_PER / (256 * 8), 256, 0, stream>>>(x, xb, QKV_PER);
    tcast_k<1><<<dim3(3 * EMBEDC / 32, EMBEDC / 32), 256, 0, stream>>>(
        w_attn, waT, EMBEDC, 3 * EMBEDC);
    tcast_k<0><<<dim3(EMBEDC / 32, EMBEDC / 32), 256, 0, stream>>>(
        w_proj, wpT, EMBEDC, EMBEDC);

    // K1: qkv = x @ w_attn + b_attn -> bf16 q/k/v [bh][t][hd]
    gemm_bf16_k<1><<<dim3(2304 / 128, 4096 / 128), 256, 0, stream>>>(
        xb, waT, b_attn, qw, NB * T_SZ, 3 * EMBEDC, EMBEDC);

    // V transpose -> [bh][hd][t]
    vt_k<<<dim3(T_SZ / 64, NB * NHEADS), 256, 0, stream>>>(
        qw + 2 * (size_t)QKV_PER, vT);

    // K2: bf16 MFMA causal flash attention (32-row q-tiles, paired, uniform)
    attn_mfma_k<<<768, 256, 0, stream>>>(
        qw, qw + QKV_PER, vT, attb);

    // K3: out = att @ w_proj + b_proj (f32 out)
    gemm_bf16_k<0><<<dim3(768 / 128, 4096 / 128), 256, 0, stream>>>(
        attb, wpT, b_proj, out, NB * T_SZ, EMBEDC, EMBEDC);
}

// Round 9
// 120.405 us; speedup vs baseline: 2.5467x; 1.0557x over previous
//
#include <hip/hip_runtime.h>
#include <hip/hip_bf16.h>
#include <math.h>

// Problem constants (GPT2Attention: B=2, T=2048, EMBED=768, 12 heads, head=64)
#define NB      2
#define T_SZ    2048
#define EMBEDC  768
#define NHEADS  12
#define HEADD   64
#define QKV_PER (NB * NHEADS * T_SZ * HEADD)   // 3,145,728 elems per q/k/v
// q pre-scale: HEAD^-0.5 * log2(e), so softmax can use exp2 directly
#define QSCALE  0.18033688011112042f

typedef __bf16 bf16x8 __attribute__((ext_vector_type(8)));
typedef float  f32x4  __attribute__((ext_vector_type(4)));

__device__ inline ushort f2bf(float x) {
    union { float f; uint u; } v; v.f = x;
    uint r = v.u + 0x7fffu + ((v.u >> 16) & 1u);   // RNE
    return (ushort)(r >> 16);
}

__device__ inline uint pack2bf(float a, float b) {   // native cvt (RNE), 2x bf16
    union { __bf16 h[2]; uint u; } t;
    t.h[0] = (__bf16)a; t.h[1] = (__bf16)b;
    return t.u;
}

__device__ inline void gload16(const ushort* g, ushort* l) {
    __builtin_amdgcn_global_load_lds(
        (const __attribute__((address_space(1))) unsigned int*)g,
        (__attribute__((address_space(3))) unsigned int*)l, 16, 0, 0);
}

// ---------------------------------------------------------------------------
// f32 -> bf16 elementwise cast (8 elems/thread)
// ---------------------------------------------------------------------------
__global__ __launch_bounds__(256) void cast_k(const float* __restrict__ in,
                                              ushort* __restrict__ out, int n)
{
    int i = (blockIdx.x * 256 + threadIdx.x) * 8;
    if (i >= n) return;
    float4 a = *(const float4*)(in + i);
    float4 b = *(const float4*)(in + i + 4);
    union { ushort u[8]; int4 v; } p;
    p.u[0] = f2bf(a.x); p.u[1] = f2bf(a.y); p.u[2] = f2bf(a.z); p.u[3] = f2bf(a.w);
    p.u[4] = f2bf(b.x); p.u[5] = f2bf(b.y); p.u[6] = f2bf(b.z); p.u[7] = f2bf(b.w);
    *(int4*)(out + i) = p.v;
}

// ---------------------------------------------------------------------------
// Transpose-cast: in[R][C] f32 -> out[C'][R] bf16, 32x32 LDS tile.
// PERM=1 relocates output row n -> mat*768 + (c%12)*64 + c/12 (c = n%768).
// ---------------------------------------------------------------------------
template <int PERM>
__global__ __launch_bounds__(256) void tcast_k(const float* __restrict__ in,
                                               ushort* __restrict__ out,
                                               int R, int C)
{
    __shared__ float t[32][33];
    const int c0 = blockIdx.x * 32, r0 = blockIdx.y * 32;
    const int tx = threadIdx.x & 31, ty = threadIdx.x >> 5;
#pragma unroll
    for (int u = 0; u < 4; ++u)
        t[ty + 8 * u][tx] = in[(size_t)(r0 + ty + 8 * u) * C + c0 + tx];
    __syncthreads();
#pragma unroll
    for (int u = 0; u < 4; ++u) {
        int n = c0 + ty + 8 * u;
        int orow = n;
        if (PERM) {
            int mat = n / EMBEDC, cc = n % EMBEDC;
            orow = mat * EMBEDC + (cc % NHEADS) * HEADD + cc / NHEADS;
        }
        out[(size_t)orow * R + r0 + tx] = f2bf(t[tx][ty + 8 * u]);
    }
}

// ---------------------------------------------------------------------------
// V transpose: in [bh][t][hd] bf16 -> out [bh][hd][t] bf16. 64x64 LDS tile.
// ---------------------------------------------------------------------------
__global__ __launch_bounds__(256) void vt_k(const ushort* __restrict__ in,
                                            ushort* __restrict__ out)
{
    __shared__ ushort tile[64][66];
    const int bh = blockIdx.y;
    const int t0 = blockIdx.x * 64;
    const int tid = threadIdx.x;
#pragma unroll
    for (int u = 0; u < 2; ++u) {
        int s = tid + 256 * u;
        int r = s >> 3, c8 = s & 7;
        *(bf16x8*)&tile[r][c8 * 8] =
            *(const bf16x8*)(in + ((size_t)bh * T_SZ + t0 + r) * HEADD + c8 * 8);
    }
    __syncthreads();
#pragma unroll
    for (int u = 0; u < 2; ++u) {
        int s = tid + 256 * u;
        int hd = s >> 3, tt = s & 7;
        union { ushort v[8]; int4 q; } pk;
#pragma unroll
        for (int j = 0; j < 8; ++j) pk.v[j] = tile[tt * 8 + j][hd];
        *(int4*)(out + ((size_t)bh * HEADD + hd) * T_SZ + t0 + tt * 8) = pk.q;
    }
}

// ---------------------------------------------------------------------------
// bf16 MFMA GEMM, 2-phase double-buffered (unchanged from round 5-8).
// ---------------------------------------------------------------------------
#define STAGE(buf, koff)                                        \
    do {                                                        \
        gload16(gA0 + (koff), &As[buf][lA0o]);                  \
        gload16(gA1 + (koff), &As[buf][lA1o]);                  \
        gload16(gB0 + (koff), &Bs[buf][lB0o]);                  \
        gload16(gB1 + (koff), &Bs[buf][lB1o]);                  \
    } while (0)

template <int MODE>
__global__ __launch_bounds__(256) void gemm_bf16_k(
    const ushort* __restrict__ A, const ushort* __restrict__ Bt,
    const float* __restrict__ bias, void* __restrict__ outp,
    int M, int N, int K)
{
    __shared__ ushort As[2][128 * 32];
    __shared__ ushort Bs[2][128 * 32];

    const int tid = threadIdx.x;
    const int w = tid >> 6, l = tid & 63;
    const int g = l >> 4, r16 = l & 15;
    const int wr = w >> 1, wc = w & 1;
    const int m0 = blockIdx.y * 128, n0 = blockIdx.x * 128;

    const int srow = l >> 2;
    const int scol = ((l & 3) ^ (srow & 3)) * 8;
    const ushort* gA0 = A + (size_t)(m0 + 32 * w + srow) * K + scol;
    const ushort* gA1 = gA0 + (size_t)16 * K;
    const ushort* gB0 = Bt + (size_t)(n0 + 32 * w + srow) * K + scol;
    const ushort* gB1 = gB0 + (size_t)16 * K;
    const int lA0o = (32 * w) * 32,      lA1o = (32 * w + 16) * 32;
    const int lB0o = lA0o,               lB1o = lA1o;

    f32x4 acc[4][4];
#pragma unroll
    for (int i = 0; i < 4; ++i)
#pragma unroll
        for (int j = 0; j < 4; ++j) acc[i][j] = (f32x4){0.f, 0.f, 0.f, 0.f};

    const int rck = (r16 & 3);

    STAGE(0, 0);
    __syncthreads();

    int cur = 0;
    for (int k0 = 0; k0 < K; k0 += 32) {
        if (k0 + 32 < K) STAGE(cur ^ 1, k0 + 32);

        const ushort* sA = As[cur];
        const ushort* sB = Bs[cur];
        bf16x8 af[4], bfr[4];
#pragma unroll
        for (int ms = 0; ms < 4; ++ms) {
            int row = 64 * wr + 16 * ms + r16;
            af[ms] = *(const bf16x8*)&sA[row * 32 + ((g ^ rck) * 8)];
        }
#pragma unroll
        for (int ns = 0; ns < 4; ++ns) {
            int row = 64 * wc + 16 * ns + r16;
            bfr[ns] = *(const bf16x8*)&sB[row * 32 + ((g ^ rck) * 8)];
        }
#pragma unroll
        for (int ms = 0; ms < 4; ++ms)
#pragma unroll
            for (int ns = 0; ns < 4; ++ns)
                acc[ms][ns] = __builtin_amdgcn_mfma_f32_16x16x32_bf16(
                    af[ms], bfr[ns], acc[ms][ns], 0, 0, 0);

        __syncthreads();
        cur ^= 1;
    }

#pragma unroll
    for (int ns = 0; ns < 4; ++ns) {
        const int n = n0 + 64 * wc + 16 * ns + r16;
        if (MODE == 0) {
            float* out = (float*)outp;
            const float bv = bias[n];
#pragma unroll
            for (int ms = 0; ms < 4; ++ms) {
                const int mb = m0 + 64 * wr + 16 * ms + 4 * g;
#pragma unroll
                for (int r = 0; r < 4; ++r)
                    out[(size_t)(mb + r) * N + n] = acc[ms][ns][r] + bv;
            }
        } else {
            ushort* ob = (ushort*)outp;
            const int mat  = n / EMBEDC;   // n is the PERMUTED column n'
            const int c    = n - mat * EMBEDC;
            const int head = c >> 6;
            const int hd   = c & 63;
            const float bv = bias[mat * EMBEDC + hd * NHEADS + head];
            const float qs = (mat == 0) ? QSCALE : 1.f;
#pragma unroll
            for (int ms = 0; ms < 4; ++ms) {
                const int mb = m0 + 64 * wr + 16 * ms + 4 * g;
#pragma unroll
                for (int r = 0; r < 4; ++r) {
                    const int m = mb + r;
                    const int b = m >> 11, t = m & 2047;
                    const size_t bh = (size_t)(b * NHEADS + head);
                    ob[(size_t)mat * QKV_PER + (bh * T_SZ + t) * HEADD + hd] =
                        f2bf((acc[ms][ns][r] + bv) * qs);
                }
            }
        }
    }
}

// ---------------------------------------------------------------------------
// bf16 MFMA flash attention — BARRIER-FREE KV LOOP, DIRECT GLOBAL->REG K/V.
// Key observation: with kv-slice-per-wave, each K row / V column is consumed
// by exactly ONE wave -> LDS staging + per-tile barriers were pure overhead.
// Wave w loads its own K-slice frags (prefetched 1 tile ahead) and V-slice
// frags (issued at tile top, consumed in PV) straight to registers; the L2
// (XCD-affinity mapping: 3 heads per XCD) serves the cross-block re-reads.
// Grid 768 = (xcd = bid&7) x (bh = xcd*3 + (bid>>3)/32) x (p = (bid>>3)&31);
// block does q-tiles {p, 63-p} (uniform 17 kv-tiles of 128). LDS only holds
// the per-q-tile merge scratch (33 KB). Softmax/pack/shuffle/merge identical
// to round 8 (verified paths).
// ---------------------------------------------------------------------------
__global__ __launch_bounds__(256) void attn_mfma_k(
    const ushort* __restrict__ Qb, const ushort* __restrict__ Kb,
    const ushort* __restrict__ Vtb, ushort* __restrict__ Out)
{
    __shared__ float fsm[4 * 2048];         // 32 KB merge images
    __shared__ float Ml[128], Ll[128];      // [wave][32 q-rows]

    const int bid = blockIdx.x;
    const int xcd = bid & 7, j = bid >> 3;  // XCD-affinity: head pinned to XCD
    const int bh = xcd * 3 + (j >> 5);
    const int p  = j & 31;
    const int bb = bh / NHEADS, head = bh % NHEADS;
    const int tid = threadIdx.x;
    const int w = tid >> 6, l = tid & 63;
    const int g = l >> 4, r16 = l & 15;
    const ushort* Qg = Qb + (size_t)bh * T_SZ * HEADD;
    const ushort* Kg = Kb + (size_t)bh * T_SZ * HEADD;
    const ushort* Vg = Vtb + (size_t)bh * HEADD * T_SZ;

    const int srcLo = ((g & 1) << 5) | r16;
    const int srcHi = srcLo + 16;
    const bool kcSel = (g >> 1) != 0;

    // wave-private K slice rows: 32w + kc*16 + r16 ; V rows d = dc*16 + r16
    const ushort* Kw = Kg + (size_t)(32 * w + r16) * HEADD;
    const ushort* Vw = Vg + (size_t)r16 * T_SZ + 32 * w + g * 8;

#define LOADK(dst, k0)                                                        \
    do {                                                                      \
        _Pragma("unroll")                                                     \
        for (int kc = 0; kc < 2; ++kc) {                                      \
            dst[kc * 2 + 0] = *(const bf16x8*)(Kw + (size_t)((k0) + kc * 16) * HEADD + g * 8);        \
            dst[kc * 2 + 1] = *(const bf16x8*)(Kw + (size_t)((k0) + kc * 16) * HEADD + (g + 4) * 8);  \
        }                                                                     \
    } while (0)

    for (int rep = 0; rep < 2; ++rep) {
        const int iq = rep ? (63 - p) : p;
        const int q0 = iq * 32;
        const int qmax = q0 + 31;
        const int nt = iq / 4 + 1;          // kv tiles of 128

        // Q B-frags (2 q sub-tiles of 16)
        bf16x8 qf[2][2];
#pragma unroll
        for (int qi = 0; qi < 2; ++qi) {
            const ushort* qp = Qg + (size_t)(q0 + qi * 16 + r16) * HEADD + g * 8;
            qf[qi][0] = *(const bf16x8*)(qp);
            qf[qi][1] = *(const bf16x8*)(qp + 32);
        }

        f32x4 o[4][2];                      // o[dc][qi]
#pragma unroll
        for (int dc = 0; dc < 4; ++dc)
#pragma unroll
            for (int qi = 0; qi < 2; ++qi) o[dc][qi] = (f32x4){0.f, 0.f, 0.f, 0.f};
        float mR[2] = {-1e30f, -1e30f}, lR[2] = {0.f, 0.f};

        bf16x8 kc0[4];
        LOADK(kc0, 0);                      // prologue K frags, tile 0

        for (int kt = 0; kt < nt; ++kt) {
            const int k0 = kt * 128;
            const int kvb = k0 + 32 * w;
            if (kvb <= qmax) {              // inactive only possible on diag
                // V frags for current tile (latency hides under QK^T+softmax)
                bf16x8 vf[4];
#pragma unroll
                for (int dc = 0; dc < 4; ++dc)
                    vf[dc] = *(const bf16x8*)(Vw + (size_t)(dc * 16) * T_SZ + k0);

                // K frags for next tile (full tile of latency)
                bf16x8 kn[4];
                if (kt + 1 < nt) LOADK(kn, k0 + 128);

                // S^T[kv-slice][q]: 2 kc x 2 qi
                f32x4 st[2][2];
#pragma unroll
                for (int kc = 0; kc < 2; ++kc)
#pragma unroll
                    for (int qi = 0; qi < 2; ++qi) {
                        f32x4 c = (f32x4){0.f, 0.f, 0.f, 0.f};
                        c = __builtin_amdgcn_mfma_f32_16x16x32_bf16(
                                kc0[kc * 2 + 0], qf[qi][0], c, 0, 0, 0);
                        c = __builtin_amdgcn_mfma_f32_16x16x32_bf16(
                                kc0[kc * 2 + 1], qf[qi][1], c, 0, 0, 0);
                        st[kc][qi] = c;
                    }

                if (kt == nt - 1) {         // causal mask (diagonal tile)
#pragma unroll
                    for (int kc = 0; kc < 2; ++kc)
#pragma unroll
                        for (int qi = 0; qi < 2; ++qi)
#pragma unroll
                            for (int r = 0; r < 4; ++r)
                                if (kvb + kc * 16 + 4 * g + r > q0 + qi * 16 + r16)
                                    st[kc][qi][r] = -1e30f;
                }

                // online softmax per qi (lane owns q-col r16; reduce across g)
                float pm[2];
#pragma unroll
                for (int qi = 0; qi < 2; ++qi) {
                    float m = fmaxf(fmaxf(st[0][qi][0], st[0][qi][1]),
                                    fmaxf(st[0][qi][2], st[0][qi][3]));
                    m = fmaxf(m, fmaxf(fmaxf(st[1][qi][0], st[1][qi][1]),
                                       fmaxf(st[1][qi][2], st[1][qi][3])));
                    m = fmaxf(m, __shfl_xor(m, 16));
                    m = fmaxf(m, __shfl_xor(m, 32));
                    pm[qi] = m;
                }
                float dm = fmaxf(pm[0] - mR[0], pm[1] - mR[1]);
                if (!__all(dm <= 8.f)) {    // T13 defer-max
#pragma unroll
                    for (int qi = 0; qi < 2; ++qi) {
                        float mNew = fmaxf(mR[qi], pm[qi]);
                        float sc = exp2f(mR[qi] - mNew);
                        lR[qi] *= sc;
                        mR[qi] = mNew;
#pragma unroll
                        for (int dc = 0; dc < 4; ++dc) o[dc][qi] *= sc;
                    }
                }
#pragma unroll
                for (int qi = 0; qi < 2; ++qi) {
                    float rs = 0.f;
#pragma unroll
                    for (int kc = 0; kc < 2; ++kc)
#pragma unroll
                        for (int r = 0; r < 4; ++r) {
                            float e = exp2f(st[kc][qi][r] - mR[qi]);
                            st[kc][qi][r] = e;
                            rs += e;
                        }
                    rs += __shfl_xor(rs, 16);
                    rs += __shfl_xor(rs, 32);
                    lR[qi] += rs;
                }

                // pack P^T
                uint pk[2][2][2];
#pragma unroll
                for (int qi = 0; qi < 2; ++qi)
#pragma unroll
                    for (int kc = 0; kc < 2; ++kc) {
                        pk[qi][kc][0] = pack2bf(st[kc][qi][0], st[kc][qi][1]);
                        pk[qi][kc][1] = pack2bf(st[kc][qi][2], st[kc][qi][3]);
                    }

                // redistribute P^T to B-frags + PV MFMAs
#pragma unroll
                for (int qi = 0; qi < 2; ++qi) {
                    uint A0 = (uint)__shfl((int)pk[qi][0][0], srcLo);
                    uint A1 = (uint)__shfl((int)pk[qi][0][1], srcLo);
                    uint B0 = (uint)__shfl((int)pk[qi][1][0], srcLo);
                    uint B1 = (uint)__shfl((int)pk[qi][1][1], srcLo);
                    uint A2 = (uint)__shfl((int)pk[qi][0][0], srcHi);
                    uint A3 = (uint)__shfl((int)pk[qi][0][1], srcHi);
                    uint B2 = (uint)__shfl((int)pk[qi][1][0], srcHi);
                    uint B3 = (uint)__shfl((int)pk[qi][1][1], srcHi);
                    union { uint u[4]; bf16x8 v; } t;
                    t.u[0] = kcSel ? B0 : A0;
                    t.u[1] = kcSel ? B1 : A1;
                    t.u[2] = kcSel ? B2 : A2;
                    t.u[3] = kcSel ? B3 : A3;
#pragma unroll
                    for (int dc = 0; dc < 4; ++dc)
                        o[dc][qi] = __builtin_amdgcn_mfma_f32_16x16x32_bf16(
                            vf[dc], t.v, o[dc][qi], 0, 0, 0);
                }

                if (kt + 1 < nt) {
#pragma unroll
                    for (int i = 0; i < 4; ++i) kc0[i] = kn[i];
                }
            }
        }

        // ---- parallel cross-wave merge (LDS only used here) ----
        __syncthreads();                    // prev rep's gather done; waves in
        if (g == 0) {
#pragma unroll
            for (int qi = 0; qi < 2; ++qi) {
                Ml[w * 32 + qi * 16 + r16] = mR[qi];
                Ll[w * 32 + qi * 16 + r16] = lR[qi];
            }
        }
        __syncthreads();

        float lt[2];
#pragma unroll
        for (int qi = 0; qi < 2; ++qi) {
            const int ix = qi * 16 + r16;
            float m0 = Ml[ix], m1 = Ml[32 + ix], m2 = Ml[64 + ix], m3 = Ml[96 + ix];
            float mt = fmaxf(fmaxf(m0, m1), fmaxf(m2, m3));
            float f = exp2f(mR[qi] - mt);
#pragma unroll
            for (int dc = 0; dc < 4; ++dc) o[dc][qi] *= f;
            lt[qi] = Ll[ix]      * exp2f(m0 - mt) + Ll[32 + ix] * exp2f(m1 - mt)
                   + Ll[64 + ix] * exp2f(m2 - mt) + Ll[96 + ix] * exp2f(m3 - mt);
        }

        // publish scaled O images (swizzled chunk: (dc*4+g)^r16)
#pragma unroll
        for (int dc = 0; dc < 4; ++dc)
#pragma unroll
            for (int qi = 0; qi < 2; ++qi)
                *(f32x4*)&fsm[w * 2048 + (qi * 16 + r16) * 64 +
                              (((dc * 4 + g) ^ r16) * 4)] = o[dc][qi];
        __syncthreads();

        // gather: wave w sums d-range [16w,16w+16) across the 4 images
#pragma unroll
        for (int qi = 0; qi < 2; ++qi) {
            const int off = (qi * 16 + r16) * 64 + (((w * 4 + g) ^ r16) * 4);
            f32x4 a = *(const f32x4*)&fsm[off];
            a += *(const f32x4*)&fsm[2048 + off];
            a += *(const f32x4*)&fsm[4096 + off];
            a += *(const f32x4*)&fsm[6144 + off];
            const float inv = 1.f / lt[qi];
            ushort4 pv;
            pv.x = f2bf(a[0] * inv);
            pv.y = f2bf(a[1] * inv);
            pv.z = f2bf(a[2] * inv);
            pv.w = f2bf(a[3] * inv);
            *(ushort4*)(Out + ((size_t)(bb * T_SZ + q0 + qi * 16 + r16)) * EMBEDC
                        + head * HEADD + w * 16 + 4 * g) = pv;
        }
    }
#undef LOADK
}

// ---------------------------------------------------------------------------
extern "C" void kernel_launch(void* const* d_in, const int* in_sizes, int n_in,
                              void* d_out, int out_size, void* d_ws, size_t ws_size,
                              hipStream_t stream)
{
    const float* x      = (const float*)d_in[0];   // [2,2048,768]
    const float* w_attn = (const float*)d_in[1];   // [768,2304]
    const float* b_attn = (const float*)d_in[2];   // [2304]
    const float* w_proj = (const float*)d_in[3];   // [768,768]
    const float* b_proj = (const float*)d_in[4];   // [768]
    float* out = (float*)d_out;                    // [2,2048,768] f32

    // Workspace (ushort units): q,k,v | vT | att | x_bf | w_attnT' | w_projT
    ushort* qw   = (ushort*)d_ws;                  // 3*QKV_PER  [mat][bh][t][hd]
    ushort* vT   = qw + (size_t)3 * QKV_PER;       // QKV_PER    [bh][hd][t]
    ushort* attb = vT + QKV_PER;                   // QKV_PER
    ushort* xb   = attb + QKV_PER;                 // QKV_PER
    ushort* waT  = xb + QKV_PER;                   // 768*2304 (col-permuted)
    ushort* wpT  = waT + (size_t)EMBEDC * 3 * EMBEDC;

    cast_k<<<QKV_PER / (256 * 8), 256, 0, stream>>>(x, xb, QKV_PER);
    tcast_k<1><<<dim3(3 * EMBEDC / 32, EMBEDC / 32), 256, 0, stream>>>(
        w_attn, waT, EMBEDC, 3 * EMBEDC);
    tcast_k<0><<<dim3(EMBEDC / 32, EMBEDC / 32), 256, 0, stream>>>(
        w_proj, wpT, EMBEDC, EMBEDC);

    // K1: qkv = x @ w_attn + b_attn -> bf16 q/k/v [bh][t][hd]
    gemm_bf16_k<1><<<dim3(2304 / 128, 4096 / 128), 256, 0, stream>>>(
        xb, waT, b_attn, qw, NB * T_SZ, 3 * EMBEDC, EMBEDC);

    // V transpose -> [bh][hd][t]
    vt_k<<<dim3(T_SZ / 64, NB * NHEADS), 256, 0, stream>>>(
        qw + 2 * (size_t)QKV_PER, vT);

    // K2: bf16 MFMA causal flash attention (barrier-free, direct-to-reg K/V)
    attn_mfma_k<<<768, 256, 0, stream>>>(
        qw, qw + QKV_PER, vT, attb);

    // K3: out = att @ w_proj + b_proj (f32 out)
    gemm_bf16_k<0><<<dim3(768 / 128, 4096 / 128), 256, 0, stream>>>(
        attb, wpT, b_proj, out, NB * T_SZ, EMBEDC, EMBEDC);
}